// Round 1
// baseline (801.787 us; speedup 1.0000x reference)
//
#include <hip/hip_runtime.h>
#include <hip/hip_bf16.h>
#include <stdint.h>

using bf16 = __bf16;
using bf16x8 = __attribute__((ext_vector_type(8))) __bf16;
using bf16x4 = __attribute__((ext_vector_type(4))) __bf16;
using f32x4  = __attribute__((ext_vector_type(4))) float;

#define MFMA16(a,b,c) __builtin_amdgcn_mfma_f32_16x16x32_bf16((a),(b),(c),0,0,0)

__device__ __forceinline__ void gll16(const void* g, void* l) {
  __builtin_amdgcn_global_load_lds(
      (const __attribute__((address_space(1))) uint32_t*)g,
      (__attribute__((address_space(3))) uint32_t*)l, 16, 0, 0);
}

// ---------------- fp32 -> bf16 convert ----------------
__global__ __launch_bounds__(256) void f32_to_bf16_k(
    const float* __restrict__ in, bf16* __restrict__ out, int n4) {
  int i = blockIdx.x * blockDim.x + threadIdx.x;
  if (i >= n4) return;
  const float4 v = ((const float4*)in)[i];
  bf16x4 o;
  o[0] = (bf16)v.x; o[1] = (bf16)v.y; o[2] = (bf16)v.z; o[3] = (bf16)v.w;
  ((bf16x4*)out)[i] = o;
}

// ---------------- GEMM: C[M,N] = A[M,K] * B[N,K]^T ----------------
// 128x128 tile, BK=32, 256 threads = 4 waves, each wave 64x64 out.
// global_load_lds width-16 staging, linear LDS (m97 structure).
template <typename OutT>
__global__ __launch_bounds__(256, 2) void gemm_bt(
    const bf16* __restrict__ A,
    const bf16* __restrict__ B0, const bf16* __restrict__ B1, const bf16* __restrict__ B2,
    OutT* __restrict__ C0, OutT* __restrict__ C1, OutT* __restrict__ C2,
    int M, int N, int K) {
  const bf16* Bm = (blockIdx.z == 0) ? B0 : (blockIdx.z == 1 ? B1 : B2);
  OutT* C = (blockIdx.z == 0) ? C0 : (blockIdx.z == 1 ? C1 : C2);

  __shared__ bf16 As[128 * 32];
  __shared__ bf16 Bs[128 * 32];

  const int t = threadIdx.x;
  const int w = t >> 6;
  const int l = t & 63;
  const int m0 = blockIdx.y * 128;
  const int n0 = blockIdx.x * 128;
  const int wr = (w >> 1) * 64;   // wave row offset in tile
  const int wc = (w & 1) * 64;    // wave col offset in tile

  f32x4 acc[4][4] = {};

  // staging: issue (w,i) covers rows (w*2+i)*16 + l/4, cols (l&3)*8
  const int srow = w * 32 + (l >> 2);
  const int scol = (l & 3) * 8;
  const bf16* Ag = A + (int64_t)(m0 + srow) * K + scol;
  const bf16* Bg = Bm + (int64_t)(n0 + srow) * K + scol;

  const int ar = (l & 15) * 32 + (l >> 4) * 8;  // frag LDS elem offset within 16-row band

  for (int k0 = 0; k0 < K; k0 += 32) {
    gll16(Ag + k0,          As + (w * 2 + 0) * 512);
    gll16(Ag + k0 + 16 * K, As + (w * 2 + 1) * 512);
    gll16(Bg + k0,          Bs + (w * 2 + 0) * 512);
    gll16(Bg + k0 + 16 * K, Bs + (w * 2 + 1) * 512);
    __syncthreads();

    bf16x8 af[4], bfr[4];
#pragma unroll
    for (int mi = 0; mi < 4; ++mi) af[mi] = *(const bf16x8*)&As[(wr + mi * 16) * 32 + ar];
#pragma unroll
    for (int ni = 0; ni < 4; ++ni) bfr[ni] = *(const bf16x8*)&Bs[(wc + ni * 16) * 32 + ar];
#pragma unroll
    for (int mi = 0; mi < 4; ++mi)
#pragma unroll
      for (int ni = 0; ni < 4; ++ni)
        acc[mi][ni] = MFMA16(af[mi], bfr[ni], acc[mi][ni]);
    __syncthreads();
  }

  // epilogue: C/D layout col=lane&15 (N), row=(lane>>4)*4+j (M)
#pragma unroll
  for (int mi = 0; mi < 4; ++mi) {
    const int row = m0 + wr + mi * 16 + (l >> 4) * 4;
#pragma unroll
    for (int ni = 0; ni < 4; ++ni) {
      const int col = n0 + wc + ni * 16 + (l & 15);
#pragma unroll
      for (int j = 0; j < 4; ++j)
        C[(int64_t)(row + j) * N + col] = (OutT)acc[mi][ni][j];
    }
  }
}

// ---------------- flash attention (causal + ALiBi + key mask) ----------------
// grid (S/64, B*H), 256 thr = 4 waves; wave handles 16 q-rows; KV tiles of 64.
__global__ __launch_bounds__(256, 2) void attn_fwd(
    const bf16* __restrict__ Q, const bf16* __restrict__ Kb,
    const bf16* __restrict__ V, const float* __restrict__ mask,
    bf16* __restrict__ O) {
  constexpr int S = 2048, D = 2048, Dh = 128;
  __shared__ bf16 Ks[64 * 128];
  __shared__ bf16 Vt[128 * 64];       // transposed: Vt[d][kv]
  __shared__ bf16 Pl[4][16 * 64];     // per-wave P buffer

  const int t = threadIdx.x, w = t >> 6, l = t & 63;
  const int q0 = blockIdx.x * 64;
  const int bh = blockIdx.y, b = bh >> 4, h = bh & 15;
  const int lq = l & 15, lk = l >> 4;

  // Q fragments (held in registers for all tiles)
  bf16x8 qf[4];
  const bf16* Qrow = Q + (int64_t)(b * S + q0 + w * 16 + lq) * D + h * Dh;
#pragma unroll
  for (int kk = 0; kk < 4; ++kk) qf[kk] = *(const bf16x8*)&Qrow[kk * 32 + lk * 8];

  float mrow[4], lrow[4];
  f32x4 oacc[8] = {};
#pragma unroll
  for (int j = 0; j < 4; ++j) { mrow[j] = -1e30f; lrow[j] = 0.f; }

  const float scale = 0.08838834764831845f;       // 1/sqrt(128)
  const float slope = exp2f(-0.5f * (float)(h + 1));

  const int ntiles = q0 / 64 + 1;
  for (int kt = 0; kt < ntiles; ++kt) {
    const int kv0 = kt * 64;

    // stage K tile via global_load_lds (linear [64][128])
#pragma unroll
    for (int i = 0; i < 4; ++i) {
      const int r = (w * 4 + i) * 4 + lk;
      gll16(Kb + (int64_t)(b * S + kv0 + r) * D + h * Dh + lq * 8,
            Ks + (w * 4 + i) * 512);
    }
    // stage V transposed (reg-staged)
#pragma unroll
    for (int c = 0; c < 4; ++c) {
      const int cid = t + 256 * c;
      const int kv = cid >> 4;
      const int d8 = (cid & 15) * 8;
      bf16x8 v8 = *(const bf16x8*)&V[(int64_t)(b * S + kv0 + kv) * D + h * Dh + d8];
#pragma unroll
      for (int jj = 0; jj < 8; ++jj) Vt[(d8 + jj) * 64 + kv] = v8[jj];
    }
    __syncthreads();

    // QK^T: sc[ni] covers kv cols ni*16+lq, q rows lk*4+j
    f32x4 sc[4];
#pragma unroll
    for (int ni = 0; ni < 4; ++ni) {
      f32x4 a = {};
#pragma unroll
      for (int kk = 0; kk < 4; ++kk) {
        bf16x8 kf = *(const bf16x8*)&Ks[(ni * 16 + lq) * 128 + kk * 32 + lk * 8];
        a = MFMA16(qf[kk], kf, a);
      }
      sc[ni] = a;
    }

    // scale + ALiBi + causal + key-mask
#pragma unroll
    for (int ni = 0; ni < 4; ++ni) {
      const int kcol = kv0 + ni * 16 + lq;
      const float mval = mask[b * S + kcol];
#pragma unroll
      for (int j = 0; j < 4; ++j) {
        const int qrow = q0 + w * 16 + lk * 4 + j;
        float s = sc[ni][j] * scale - slope * (float)(qrow - kcol);
        if (kcol > qrow) s = -1e30f;
        sc[ni][j] = s * mval;
      }
    }

    // online softmax, per q-row j (row spread over 16 lanes lq within lk group)
#pragma unroll
    for (int j = 0; j < 4; ++j) {
      float mj = fmaxf(fmaxf(sc[0][j], sc[1][j]), fmaxf(sc[2][j], sc[3][j]));
#pragma unroll
      for (int d = 1; d < 16; d <<= 1) mj = fmaxf(mj, __shfl_xor(mj, d));
      const float mnew = fmaxf(mrow[j], mj);
      const float r = __expf(mrow[j] - mnew);
      mrow[j] = mnew;
      float ps = 0.f;
#pragma unroll
      for (int ni = 0; ni < 4; ++ni) {
        const float p = __expf(sc[ni][j] - mnew);
        sc[ni][j] = p;
        ps += p;
      }
#pragma unroll
      for (int d = 1; d < 16; d <<= 1) ps += __shfl_xor(ps, d);
      lrow[j] = lrow[j] * r + ps;
#pragma unroll
      for (int df = 0; df < 8; ++df) oacc[df][j] *= r;
    }

    // P -> LDS (re-fragment for PV's A operand)
#pragma unroll
    for (int ni = 0; ni < 4; ++ni)
#pragma unroll
      for (int j = 0; j < 4; ++j)
        Pl[w][(lk * 4 + j) * 64 + ni * 16 + lq] = (bf16)sc[ni][j];

    bf16x8 pf[2];
#pragma unroll
    for (int k2 = 0; k2 < 2; ++k2)
      pf[k2] = *(const bf16x8*)&Pl[w][lq * 64 + k2 * 32 + lk * 8];

    // PV: oacc[df] over d cols df*16+lq
#pragma unroll
    for (int df = 0; df < 8; ++df) {
#pragma unroll
      for (int k2 = 0; k2 < 2; ++k2) {
        bf16x8 vf = *(const bf16x8*)&Vt[(df * 16 + lq) * 64 + k2 * 32 + lk * 8];
        oacc[df] = MFMA16(pf[k2], vf, oacc[df]);
      }
    }
    __syncthreads();
  }

  // epilogue: normalize and store bf16 attn output [B*S][D]
#pragma unroll
  for (int df = 0; df < 8; ++df) {
#pragma unroll
    for (int j = 0; j < 4; ++j) {
      const float o = oacc[df][j] / lrow[j];
      O[(int64_t)(b * S + q0 + w * 16 + lk * 4 + j) * D + h * Dh + df * 16 + lq] = (bf16)o;
    }
  }
}

// ---------------- launch ----------------
extern "C" void kernel_launch(void* const* d_in, const int* in_sizes, int n_in,
                              void* d_out, int out_size, void* d_ws, size_t ws_size,
                              hipStream_t stream) {
  const float* X    = (const float*)d_in[0];
  const float* mask = (const float*)d_in[1];
  const float* Wq   = (const float*)d_in[2];
  const float* Wk   = (const float*)d_in[3];
  const float* Wv   = (const float*)d_in[4];
  const float* Wo   = (const float*)d_in[5];
  float* out = (float*)d_out;

  bf16* ws = (bf16*)d_ws;
  bf16* Xb  = ws;                 // 4096*2048
  bf16* Wqb = ws + 8388608;       // 2048*2048 each
  bf16* Wkb = ws + 12582912;
  bf16* Wvb = ws + 16777216;
  bf16* Wob = ws + 20971520;
  bf16* Qb  = ws + 25165824;      // 4096*2048 each
  bf16* Kb  = ws + 33554432;
  bf16* Vb  = ws + 41943040;
  bf16* Ab  = ws + 50331648;      // 4096*2048

  f32_to_bf16_k<<<8192, 256, 0, stream>>>(X,  Xb,  2097152);
  f32_to_bf16_k<<<4096, 256, 0, stream>>>(Wq, Wqb, 1048576);
  f32_to_bf16_k<<<4096, 256, 0, stream>>>(Wk, Wkb, 1048576);
  f32_to_bf16_k<<<4096, 256, 0, stream>>>(Wv, Wvb, 1048576);
  f32_to_bf16_k<<<4096, 256, 0, stream>>>(Wo, Wob, 1048576);

  // fused QKV projection: grid.z selects weight/output
  gemm_bt<bf16><<<dim3(16, 32, 3), 256, 0, stream>>>(
      Xb, Wqb, Wkb, Wvb, Qb, Kb, Vb, 4096, 2048, 2048);

  attn_fwd<<<dim3(32, 32), 256, 0, stream>>>(Qb, Kb, Vb, mask, Ab);

  // output projection -> fp32 d_out
  gemm_bt<float><<<dim3(16, 32, 1), 256, 0, stream>>>(
      Ab, Wob, Wob, Wob, out, out, out, 4096, 2048, 2048);
}

// Round 3
// 519.962 us; speedup vs baseline: 1.5420x; 1.5420x over previous
//
#include <hip/hip_runtime.h>
#include <hip/hip_bf16.h>
#include <stdint.h>

using bf16 = __bf16;
using bf16x8 = __attribute__((ext_vector_type(8))) __bf16;
using bf16x4 = __attribute__((ext_vector_type(4))) __bf16;
using f32x4  = __attribute__((ext_vector_type(4))) float;
using u16x8  = __attribute__((ext_vector_type(8))) unsigned short;

#define MFMA16(a,b,c) __builtin_amdgcn_mfma_f32_16x16x32_bf16((a),(b),(c),0,0,0)

__device__ __forceinline__ void gll16(const void* g, void* l) {
  __builtin_amdgcn_global_load_lds(
      (const __attribute__((address_space(1))) uint32_t*)g,
      (__attribute__((address_space(3))) uint32_t*)l, 16, 0, 0);
}

// ---------------- fp32 -> bf16 convert ----------------
__global__ __launch_bounds__(256) void f32_to_bf16_k(
    const float* __restrict__ in, bf16* __restrict__ out, int n4) {
  int i = blockIdx.x * blockDim.x + threadIdx.x;
  if (i >= n4) return;
  const float4 v = ((const float4*)in)[i];
  bf16x4 o;
  o[0] = (bf16)v.x; o[1] = (bf16)v.y; o[2] = (bf16)v.z; o[3] = (bf16)v.w;
  ((bf16x4*)out)[i] = o;
}

// ---------------- GEMM: C[M,N] = A[M,K] * B[N,K]^T ----------------
// 128x128 tile, BK=32, 256 threads = 4 waves, each wave 64x64 out. (m97 structure)
template <typename OutT>
__global__ __launch_bounds__(256, 2) void gemm_bt(
    const bf16* __restrict__ A,
    const bf16* __restrict__ B0, const bf16* __restrict__ B1, const bf16* __restrict__ B2,
    OutT* __restrict__ C0, OutT* __restrict__ C1, OutT* __restrict__ C2,
    int M, int N, int K) {
  const bf16* Bm = (blockIdx.z == 0) ? B0 : (blockIdx.z == 1 ? B1 : B2);
  OutT* C = (blockIdx.z == 0) ? C0 : (blockIdx.z == 1 ? C1 : C2);

  __shared__ bf16 As[128 * 32];
  __shared__ bf16 Bs[128 * 32];

  const int t = threadIdx.x;
  const int w = t >> 6;
  const int l = t & 63;
  const int m0 = blockIdx.y * 128;
  const int n0 = blockIdx.x * 128;
  const int wr = (w >> 1) * 64;
  const int wc = (w & 1) * 64;

  f32x4 acc[4][4] = {};

  const int srow = w * 32 + (l >> 2);
  const int scol = (l & 3) * 8;
  const bf16* Ag = A + (int64_t)(m0 + srow) * K + scol;
  const bf16* Bg = Bm + (int64_t)(n0 + srow) * K + scol;

  const int ar = (l & 15) * 32 + (l >> 4) * 8;

  for (int k0 = 0; k0 < K; k0 += 32) {
    gll16(Ag + k0,          As + (w * 2 + 0) * 512);
    gll16(Ag + k0 + 16 * K, As + (w * 2 + 1) * 512);
    gll16(Bg + k0,          Bs + (w * 2 + 0) * 512);
    gll16(Bg + k0 + 16 * K, Bs + (w * 2 + 1) * 512);
    __syncthreads();

    bf16x8 af[4], bfr[4];
#pragma unroll
    for (int mi = 0; mi < 4; ++mi) af[mi] = *(const bf16x8*)&As[(wr + mi * 16) * 32 + ar];
#pragma unroll
    for (int ni = 0; ni < 4; ++ni) bfr[ni] = *(const bf16x8*)&Bs[(wc + ni * 16) * 32 + ar];
#pragma unroll
    for (int mi = 0; mi < 4; ++mi)
#pragma unroll
      for (int ni = 0; ni < 4; ++ni)
        acc[mi][ni] = MFMA16(af[mi], bfr[ni], acc[mi][ni]);
    __syncthreads();
  }

#pragma unroll
  for (int mi = 0; mi < 4; ++mi) {
    const int row = m0 + wr + mi * 16 + (l >> 4) * 4;
#pragma unroll
    for (int ni = 0; ni < 4; ++ni) {
      const int col = n0 + wc + ni * 16 + (l & 15);
#pragma unroll
      for (int j = 0; j < 4; ++j)
        C[(int64_t)(row + j) * N + col] = (OutT)acc[mi][ni][j];
    }
  }
}

// ---------------- flash attention (causal + ALiBi + key mask) ----------------
// grid (32, B*H), 256 thr = 4 waves; wave handles 16 q-rows; KV tiles of 64.
// Double-buffered K (gll16, source-preswizzled) + V (reg-staged, packed-u32
// transpose writes). All LDS access patterns conflict-free by construction.
__global__ __launch_bounds__(256, 2) void attn_fwd(
    const bf16* __restrict__ Q, const bf16* __restrict__ Kb,
    const bf16* __restrict__ V, const float* __restrict__ mask,
    bf16* __restrict__ O) {
  constexpr int S = 2048, D = 2048, Dh = 128;
  // Ks: logical [64][128] bf16, phys byte = row*256 + (col2B ^ ((row&7)<<4))
  // Vt: logical [128][64] bf16 (V^T), phys byte = d*128 + (kv2B ^ ((d&7)<<4))
  __shared__ bf16 Ks[2][64 * 128];
  __shared__ bf16 Vt[2][128 * 64];
  __shared__ bf16 Pl[4][16 * 68];   // stride 68: conflict-free writes/reads

  const int t = threadIdx.x, w = t >> 6, l = t & 63;
  const int lq = l & 15, lk = l >> 4;
  const int qt = 31 - blockIdx.x;   // longest-first for causal balance
  const int q0 = qt * 64;
  const int bh = blockIdx.y, b = bh >> 4, h = bh & 15;
  const int swz = (lq & 7) << 4;

  // V staging assignment: this thread owns kv pair {2*kvp, 2*kvp+1},
  // d-chunks d80 (=8*(t>>5)) and d81 (=d80+64), 8 d-elems each.
  const int kvp = t & 31;
  const int d80 = (t >> 5) * 8;
  const int d81 = d80 + 64;

  // Q fragments (registers, reused for all tiles)
  bf16x8 qf[4];
  {
    const bf16* Qrow = Q + (int64_t)(b * S + q0 + w * 16 + lq) * D + h * Dh;
#pragma unroll
    for (int kk = 0; kk < 4; ++kk) qf[kk] = *(const bf16x8*)&Qrow[kk * 32 + lk * 8];
  }

  float mrow[4], lrow[4];
  f32x4 oacc[8] = {};
#pragma unroll
  for (int j = 0; j < 4; ++j) { mrow[j] = -1e30f; lrow[j] = 0.f; }

  const float scale = 0.08838834764831845f;   // 1/sqrt(128)
  const float slope = exp2f(-0.5f * (float)(h + 1));
  const int ntiles = qt + 1;

  bf16x8 vA0, vA1, vB0, vB1;   // V prefetch regs (named: static indexing)

#define LOAD_V(kt)                                                          \
  {                                                                         \
    const bf16* vb = V + (int64_t)(b * S + (kt) * 64 + 2 * kvp) * D + h * Dh; \
    vA0 = *(const bf16x8*)(vb + d80);                                       \
    vA1 = *(const bf16x8*)(vb + D + d80);                                   \
    vB0 = *(const bf16x8*)(vb + d81);                                       \
    vB1 = *(const bf16x8*)(vb + D + d81);                                   \
  }

#define STAGE_K(kt, buf)                                                    \
  {                                                                         \
    _Pragma("unroll")                                                       \
    for (int i = 0; i < 4; ++i) {                                           \
      const int chunk = 4 * w + i;                                          \
      const int r = chunk * 4 + (l >> 4);                                   \
      const int cbl = ((l & 15) * 16) ^ ((r & 7) << 4);                     \
      gll16(Kb + (int64_t)(b * S + (kt) * 64 + r) * D + h * Dh + (cbl >> 1),\
            &Ks[buf][chunk * 512]);                                         \
    }                                                                       \
  }

#define WRITE_V(buf)                                                        \
  {                                                                         \
    const u16x8 u00 = __builtin_bit_cast(u16x8, vA0);                       \
    const u16x8 u01 = __builtin_bit_cast(u16x8, vA1);                       \
    const u16x8 u10 = __builtin_bit_cast(u16x8, vB0);                       \
    const u16x8 u11 = __builtin_bit_cast(u16x8, vB1);                       \
    char* vtb = (char*)&Vt[buf][0];                                         \
    _Pragma("unroll")                                                       \
    for (int jj = 0; jj < 8; ++jj) {                                        \
      const int co = (4 * kvp) ^ (jj << 4);                                 \
      *(uint32_t*)(vtb + (d80 + jj) * 128 + co) =                           \
          (uint32_t)u00[jj] | ((uint32_t)u01[jj] << 16);                    \
      *(uint32_t*)(vtb + (d81 + jj) * 128 + co) =                           \
          (uint32_t)u10[jj] | ((uint32_t)u11[jj] << 16);                    \
    }                                                                       \
  }

  // prologue: stage tile 0
  LOAD_V(0);
  STAGE_K(0, 0);
  WRITE_V(0);
  __syncthreads();

  for (int kt = 0; kt < ntiles; ++kt) {
    const int cb = kt & 1, nb = cb ^ 1;
    const int kv0 = kt * 64;
    const bool pft = (kt + 1 < ntiles);
    if (pft) {         // issue next tile's loads early (hide under compute)
      STAGE_K(kt + 1, nb);
      LOAD_V(kt + 1);
    }

    // QK^T: sc[ni] covers kv cols ni*16+lq, q rows lk*4+j (swizzled reads)
    f32x4 sc[4];
#pragma unroll
    for (int ni = 0; ni < 4; ++ni) {
      const char* krow = (const char*)&Ks[cb][(ni * 16 + lq) * 128];
      f32x4 a = {};
#pragma unroll
      for (int kk = 0; kk < 4; ++kk) {
        bf16x8 kf = *(const bf16x8*)(krow + ((kk * 64 + lk * 16) ^ swz));
        a = MFMA16(qf[kk], kf, a);
      }
      sc[ni] = a;
    }

    // scale + ALiBi + causal + key-mask
#pragma unroll
    for (int ni = 0; ni < 4; ++ni) {
      const int kcol = kv0 + ni * 16 + lq;
      const float mval = mask[b * S + kcol];
#pragma unroll
      for (int j = 0; j < 4; ++j) {
        const int qrow = q0 + w * 16 + lk * 4 + j;
        float s = sc[ni][j] * scale - slope * (float)(qrow - kcol);
        s = (kcol > qrow) ? -1e30f : s;
        sc[ni][j] = s * mval;
      }
    }

    // online softmax per q-row j (row spread over 16 lanes lq)
#pragma unroll
    for (int j = 0; j < 4; ++j) {
      float mj = fmaxf(fmaxf(sc[0][j], sc[1][j]), fmaxf(sc[2][j], sc[3][j]));
#pragma unroll
      for (int d = 1; d < 16; d <<= 1) mj = fmaxf(mj, __shfl_xor(mj, d));
      const float mnew = fmaxf(mrow[j], mj);
      const float r = __expf(mrow[j] - mnew);
      mrow[j] = mnew;
      float ps = 0.f;
#pragma unroll
      for (int ni = 0; ni < 4; ++ni) {
        const float p = __expf(sc[ni][j] - mnew);
        sc[ni][j] = p;
        ps += p;
      }
#pragma unroll
      for (int d = 1; d < 16; d <<= 1) ps += __shfl_xor(ps, d);
      lrow[j] = lrow[j] * r + ps;
#pragma unroll
      for (int df = 0; df < 8; ++df) oacc[df][j] *= r;
    }

    // P -> per-wave LDS (stride 68, conflict-free), re-fragment for PV
#pragma unroll
    for (int ni = 0; ni < 4; ++ni)
#pragma unroll
      for (int j = 0; j < 4; ++j)
        Pl[w][(lk * 4 + j) * 68 + ni * 16 + lq] = (bf16)sc[ni][j];

    bf16x8 pf[2];
#pragma unroll
    for (int k2 = 0; k2 < 2; ++k2)
      pf[k2] = *(const bf16x8*)&Pl[w][lq * 68 + k2 * 32 + lk * 8];

    // PV: oacc[df] over d cols df*16+lq (swizzled V^T reads)
#pragma unroll
    for (int df = 0; df < 8; ++df) {
      const char* vrow = (const char*)&Vt[cb][(df * 16 + lq) * 64];
#pragma unroll
      for (int k2 = 0; k2 < 2; ++k2) {
        bf16x8 vf = *(const bf16x8*)(vrow + ((k2 * 64 + lk * 16) ^ swz));
        oacc[df] = MFMA16(pf[k2], vf, oacc[df]);
      }
    }

    if (pft) WRITE_V(nb);   // V regs -> LDS (other buffer) just before barrier
    __syncthreads();
  }

  // epilogue: normalize and store bf16 attn output [B*S][D]
#pragma unroll
  for (int df = 0; df < 8; ++df) {
#pragma unroll
    for (int j = 0; j < 4; ++j) {
      const float o = oacc[df][j] / lrow[j];
      O[(int64_t)(b * S + q0 + w * 16 + lk * 4 + j) * D + h * Dh + df * 16 + lq] = (bf16)o;
    }
  }
#undef LOAD_V
#undef STAGE_K
#undef WRITE_V
}

// ---------------- launch ----------------
extern "C" void kernel_launch(void* const* d_in, const int* in_sizes, int n_in,
                              void* d_out, int out_size, void* d_ws, size_t ws_size,
                              hipStream_t stream) {
  const float* X    = (const float*)d_in[0];
  const float* mask = (const float*)d_in[1];
  const float* Wq   = (const float*)d_in[2];
  const float* Wk   = (const float*)d_in[3];
  const float* Wv   = (const float*)d_in[4];
  const float* Wo   = (const float*)d_in[5];
  float* out = (float*)d_out;

  bf16* ws = (bf16*)d_ws;
  bf16* Xb  = ws;                 // 4096*2048
  bf16* Wqb = ws + 8388608;       // 2048*2048 each
  bf16* Wkb = ws + 12582912;
  bf16* Wvb = ws + 16777216;
  bf16* Wob = ws + 20971520;
  bf16* Qb  = ws + 25165824;      // 4096*2048 each
  bf16* Kb  = ws + 33554432;
  bf16* Vb  = ws + 41943040;
  bf16* Ab  = ws + 50331648;      // 4096*2048

  f32_to_bf16_k<<<8192, 256, 0, stream>>>(X,  Xb,  2097152);
  f32_to_bf16_k<<<4096, 256, 0, stream>>>(Wq, Wqb, 1048576);
  f32_to_bf16_k<<<4096, 256, 0, stream>>>(Wk, Wkb, 1048576);
  f32_to_bf16_k<<<4096, 256, 0, stream>>>(Wv, Wvb, 1048576);
  f32_to_bf16_k<<<4096, 256, 0, stream>>>(Wo, Wob, 1048576);

  gemm_bt<bf16><<<dim3(16, 32, 3), 256, 0, stream>>>(
      Xb, Wqb, Wkb, Wvb, Qb, Kb, Vb, 4096, 2048, 2048);

  attn_fwd<<<dim3(32, 32), 256, 0, stream>>>(Qb, Kb, Vb, mask, Ab);

  gemm_bt<float><<<dim3(16, 32, 1), 256, 0, stream>>>(
      Ab, Wob, Wob, Wob, out, out, out, 4096, 2048, 2048);
}

// Round 4
// 435.281 us; speedup vs baseline: 1.8420x; 1.1945x over previous
//
#include <hip/hip_runtime.h>
#include <hip/hip_bf16.h>
#include <stdint.h>

using bf16 = __bf16;
using bf16x8 = __attribute__((ext_vector_type(8))) __bf16;
using bf16x4 = __attribute__((ext_vector_type(4))) __bf16;
using f32x4  = __attribute__((ext_vector_type(4))) float;
using u16x8  = __attribute__((ext_vector_type(8))) unsigned short;

#define MFMA16(a,b,c) __builtin_amdgcn_mfma_f32_16x16x32_bf16((a),(b),(c),0,0,0)

__device__ __forceinline__ void gll16(const void* g, void* l) {
  __builtin_amdgcn_global_load_lds(
      (const __attribute__((address_space(1))) uint32_t*)g,
      (__attribute__((address_space(3))) uint32_t*)l, 16, 0, 0);
}

// ---------------- fp32 -> bf16 convert ----------------
__global__ __launch_bounds__(256) void f32_to_bf16_k(
    const float* __restrict__ in, bf16* __restrict__ out, int n4) {
  int i = blockIdx.x * blockDim.x + threadIdx.x;
  if (i >= n4) return;
  const float4 v = ((const float4*)in)[i];
  bf16x4 o;
  o[0] = (bf16)v.x; o[1] = (bf16)v.y; o[2] = (bf16)v.z; o[3] = (bf16)v.w;
  ((bf16x4*)out)[i] = o;
}

// ---------------- GEMM: C[M,N] = A[M,K] * B[N,K]^T ----------------
// 128x128 tile, BK=32, 256 threads = 4 waves, each wave 64x64 out. (m97 structure)
// T1: bijective XCD-aware block swizzle (nwg % 8 == 0 for all our launches).
template <typename OutT>
__global__ __launch_bounds__(256, 2) void gemm_bt(
    const bf16* __restrict__ A,
    const bf16* __restrict__ B0, const bf16* __restrict__ B1, const bf16* __restrict__ B2,
    OutT* __restrict__ C0, OutT* __restrict__ C1, OutT* __restrict__ C2,
    int M, int N, int K) {
  const int gx = gridDim.x, gy = gridDim.y;
  const int nwg = gx * gy * gridDim.z;
  int lid = blockIdx.x + gx * (blockIdx.y + gy * blockIdx.z);
  lid = (lid & 7) * (nwg >> 3) + (lid >> 3);          // XCD chunking
  const int bz = lid / (gx * gy);
  const int rem = lid - bz * (gx * gy);
  const int by = rem / gx, bx = rem - by * gx;

  const bf16* Bm = (bz == 0) ? B0 : (bz == 1 ? B1 : B2);
  OutT* C = (bz == 0) ? C0 : (bz == 1 ? C1 : C2);

  __shared__ bf16 As[128 * 32];
  __shared__ bf16 Bs[128 * 32];

  const int t = threadIdx.x;
  const int w = t >> 6;
  const int l = t & 63;
  const int m0 = by * 128;
  const int n0 = bx * 128;
  const int wr = (w >> 1) * 64;
  const int wc = (w & 1) * 64;

  f32x4 acc[4][4] = {};

  const int srow = w * 32 + (l >> 2);
  const int scol = (l & 3) * 8;
  const bf16* Ag = A + (int64_t)(m0 + srow) * K + scol;
  const bf16* Bg = Bm + (int64_t)(n0 + srow) * K + scol;

  const int ar = (l & 15) * 32 + (l >> 4) * 8;

  for (int k0 = 0; k0 < K; k0 += 32) {
    gll16(Ag + k0,          As + (w * 2 + 0) * 512);
    gll16(Ag + k0 + 16 * K, As + (w * 2 + 1) * 512);
    gll16(Bg + k0,          Bs + (w * 2 + 0) * 512);
    gll16(Bg + k0 + 16 * K, Bs + (w * 2 + 1) * 512);
    __syncthreads();

    bf16x8 af[4], bfr[4];
#pragma unroll
    for (int mi = 0; mi < 4; ++mi) af[mi] = *(const bf16x8*)&As[(wr + mi * 16) * 32 + ar];
#pragma unroll
    for (int ni = 0; ni < 4; ++ni) bfr[ni] = *(const bf16x8*)&Bs[(wc + ni * 16) * 32 + ar];
#pragma unroll
    for (int mi = 0; mi < 4; ++mi)
#pragma unroll
      for (int ni = 0; ni < 4; ++ni)
        acc[mi][ni] = MFMA16(af[mi], bfr[ni], acc[mi][ni]);
    __syncthreads();
  }

#pragma unroll
  for (int mi = 0; mi < 4; ++mi) {
    const int row = m0 + wr + mi * 16 + (l >> 4) * 4;
#pragma unroll
    for (int ni = 0; ni < 4; ++ni) {
      const int col = n0 + wc + ni * 16 + (l & 15);
#pragma unroll
      for (int j = 0; j < 4; ++j)
        C[(int64_t)(row + j) * N + col] = (OutT)acc[mi][ni][j];
    }
  }
}

// ---------------- flash attention (causal + ALiBi + key mask) ----------------
// grid (32, 32), 256 thr = 4 waves; wave handles 16 q-rows; KV tiles of 64.
// SWAPPED-operand MFMAs: QK^T = mfma(K,Q) -> lane owns ONE q-row (col=lane&15),
// 16 kv values in regs -> softmax is lane-local + 2 shfls. PV = mfma(V^T,P) so
// O's q index is also lane-local (rescale/normalize shuffle-free).
__global__ __launch_bounds__(256, 2) void attn_fwd(
    const bf16* __restrict__ Q, const bf16* __restrict__ Kb,
    const bf16* __restrict__ V, const float* __restrict__ mask,
    bf16* __restrict__ O) {
  constexpr int S = 2048, D = 2048, Dh = 128;
  // Ks: logical [64][128] bf16, phys byte = row*256 + (col2B ^ ((row&7)<<4))
  // Vt: logical [128][64] bf16 (V^T), phys byte = d*128 + (kv2B ^ ((d&7)<<4))
  __shared__ bf16 Ks[2][64 * 128];
  __shared__ bf16 Vt[2][128 * 64];
  __shared__ bf16 Pl[4][16 * 68];   // per-wave P buffer, stride 68

  const int t = threadIdx.x, w = t >> 6, l = t & 63;
  const int lq = l & 15, lk = l >> 4;

  // T1 XCD swizzle: consecutive ids share bh -> per-XCD KV stays L2-resident
  const int nwg = gridDim.x * gridDim.y;                 // 1024
  int lid = blockIdx.x + gridDim.x * blockIdx.y;
  lid = (lid & 7) * (nwg >> 3) + (lid >> 3);
  const int bx = lid & 31, by = lid >> 5;

  const int qt = 31 - bx;   // longest-first for causal balance
  const int q0 = qt * 64;
  const int b = by >> 4, h = by & 15;
  const int swz = (lq & 7) << 4;

  const int kvp = t & 31;
  const int d80 = (t >> 5) * 8;
  const int d81 = d80 + 64;

  // Q fragments (registers, reused for all tiles; B-operand: col = q = w*16+lq)
  bf16x8 qf[4];
  {
    const bf16* Qrow = Q + (int64_t)(b * S + q0 + w * 16 + lq) * D + h * Dh;
#pragma unroll
    for (int kk = 0; kk < 4; ++kk) qf[kk] = *(const bf16x8*)&Qrow[kk * 32 + lk * 8];
  }

  float mr = -1e30f, lr = 0.f;      // per-lane softmax state (one q-row/lane)
  f32x4 oacc[8] = {};

  const float scale = 0.08838834764831845f;   // 1/sqrt(128)
  const float slope = exp2f(-0.5f * (float)(h + 1));
  const int ntiles = qt + 1;
  const int qrow = q0 + w * 16 + lq;          // this lane's q row

  bf16x8 vA0, vA1, vB0, vB1;

#define LOAD_V(kt)                                                          \
  {                                                                         \
    const bf16* vb = V + (int64_t)(b * S + (kt) * 64 + 2 * kvp) * D + h * Dh; \
    vA0 = *(const bf16x8*)(vb + d80);                                       \
    vA1 = *(const bf16x8*)(vb + D + d80);                                   \
    vB0 = *(const bf16x8*)(vb + d81);                                       \
    vB1 = *(const bf16x8*)(vb + D + d81);                                   \
  }

#define STAGE_K(kt, buf)                                                    \
  {                                                                         \
    _Pragma("unroll")                                                       \
    for (int i = 0; i < 4; ++i) {                                           \
      const int chunk = 4 * w + i;                                          \
      const int r = chunk * 4 + (l >> 4);                                   \
      const int cbl = ((l & 15) * 16) ^ ((r & 7) << 4);                     \
      gll16(Kb + (int64_t)(b * S + (kt) * 64 + r) * D + h * Dh + (cbl >> 1),\
            &Ks[buf][chunk * 512]);                                         \
    }                                                                       \
  }

#define WRITE_V(buf)                                                        \
  {                                                                         \
    const u16x8 u00 = __builtin_bit_cast(u16x8, vA0);                       \
    const u16x8 u01 = __builtin_bit_cast(u16x8, vA1);                       \
    const u16x8 u10 = __builtin_bit_cast(u16x8, vB0);                       \
    const u16x8 u11 = __builtin_bit_cast(u16x8, vB1);                       \
    char* vtb = (char*)&Vt[buf][0];                                         \
    _Pragma("unroll")                                                       \
    for (int jj = 0; jj < 8; ++jj) {                                        \
      const int co = (4 * kvp) ^ (jj << 4);                                 \
      *(uint32_t*)(vtb + (d80 + jj) * 128 + co) =                           \
          (uint32_t)u00[jj] | ((uint32_t)u01[jj] << 16);                    \
      *(uint32_t*)(vtb + (d81 + jj) * 128 + co) =                           \
          (uint32_t)u10[jj] | ((uint32_t)u11[jj] << 16);                    \
    }                                                                       \
  }

  LOAD_V(0);
  STAGE_K(0, 0);
  WRITE_V(0);
  __syncthreads();

  for (int kt = 0; kt < ntiles; ++kt) {
    const int cb = kt & 1, nb = cb ^ 1;
    const int kv0 = kt * 64;
    const bool pft = (kt + 1 < ntiles);
    if (pft) {
      STAGE_K(kt + 1, nb);
      LOAD_V(kt + 1);
    }

    // QK^T swapped: sc[ni][j] = S[kv = kv0+ni*16+lk*4+j][q = qrow]
    f32x4 sc[4];
#pragma unroll
    for (int ni = 0; ni < 4; ++ni) {
      const char* krow = (const char*)&Ks[cb][(ni * 16 + lq) * 128];
      f32x4 a = {};
#pragma unroll
      for (int kk = 0; kk < 4; ++kk) {
        bf16x8 kf = *(const bf16x8*)(krow + ((kk * 64 + lk * 16) ^ swz));
        a = MFMA16(kf, qf[kk], a);   // A=K (rows kv), B=Q (cols q)
      }
      sc[ni] = a;
    }

    // scale + ALiBi + causal + key-mask (all lane-local; q fixed per lane)
#pragma unroll
    for (int ni = 0; ni < 4; ++ni) {
      const float4 mv = *(const float4*)&mask[b * S + kv0 + ni * 16 + lk * 4];
      const float* mvp = (const float*)&mv;
#pragma unroll
      for (int j = 0; j < 4; ++j) {
        const int kcol = kv0 + ni * 16 + lk * 4 + j;
        float s = sc[ni][j] * scale - slope * (float)(qrow - kcol);
        s = (kcol > qrow) ? -1e30f : s;
        sc[ni][j] = s * mvp[j];
      }
    }

    // online softmax: lane-local max/sum over 16 regs + 2 shfls (xor 16,32)
    float mj = sc[0][0];
#pragma unroll
    for (int ni = 0; ni < 4; ++ni)
#pragma unroll
      for (int j = 0; j < 4; ++j) mj = fmaxf(mj, sc[ni][j]);
    mj = fmaxf(mj, __shfl_xor(mj, 16));
    mj = fmaxf(mj, __shfl_xor(mj, 32));
    const float mnew = fmaxf(mr, mj);
    const float r = __expf(mr - mnew);
    mr = mnew;
    float ps = 0.f;
#pragma unroll
    for (int ni = 0; ni < 4; ++ni)
#pragma unroll
      for (int j = 0; j < 4; ++j) {
        const float p = __expf(sc[ni][j] - mnew);
        sc[ni][j] = p;
        ps += p;
      }
    ps += __shfl_xor(ps, 16);
    ps += __shfl_xor(ps, 32);
    lr = lr * r + ps;
#pragma unroll
    for (int df = 0; df < 8; ++df)
#pragma unroll
      for (int j = 0; j < 4; ++j) oacc[df][j] *= r;

    // P -> per-wave LDS: 4x packed 8B writes (kv-contiguous quads)
#pragma unroll
    for (int ni = 0; ni < 4; ++ni) {
      bf16x4 pb;
#pragma unroll
      for (int j = 0; j < 4; ++j) pb[j] = (bf16)sc[ni][j];
      *(bf16x4*)&Pl[w][lq * 68 + ni * 16 + lk * 4] = pb;
    }

    bf16x8 pf0 = *(const bf16x8*)&Pl[w][lq * 68 + lk * 8];
    bf16x8 pf1 = *(const bf16x8*)&Pl[w][lq * 68 + 32 + lk * 8];

    // PV swapped: A=V^T (rows d), B=P (cols q) -> oacc[df][j]=O[q][df*16+lk*4+j]
#pragma unroll
    for (int df = 0; df < 8; ++df) {
      const char* vrow = (const char*)&Vt[cb][(df * 16 + lq) * 64];
      bf16x8 vf0 = *(const bf16x8*)(vrow + ((lk * 16) ^ swz));
      oacc[df] = MFMA16(vf0, pf0, oacc[df]);
      bf16x8 vf1 = *(const bf16x8*)(vrow + ((64 + lk * 16) ^ swz));
      oacc[df] = MFMA16(vf1, pf1, oacc[df]);
    }

    if (pft) WRITE_V(nb);
    __syncthreads();
  }

  // epilogue: normalize (lane-local) and store 8B chunks
  const float inv = 1.0f / lr;
  bf16* orow = O + (int64_t)(b * S + qrow) * D + h * Dh;
#pragma unroll
  for (int df = 0; df < 8; ++df) {
    bf16x4 ob;
#pragma unroll
    for (int j = 0; j < 4; ++j) ob[j] = (bf16)(oacc[df][j] * inv);
    *(bf16x4*)&orow[df * 16 + lk * 4] = ob;
  }
#undef LOAD_V
#undef STAGE_K
#undef WRITE_V
}

// ---------------- launch ----------------
extern "C" void kernel_launch(void* const* d_in, const int* in_sizes, int n_in,
                              void* d_out, int out_size, void* d_ws, size_t ws_size,
                              hipStream_t stream) {
  const float* X    = (const float*)d_in[0];
  const float* mask = (const float*)d_in[1];
  const float* Wq   = (const float*)d_in[2];
  const float* Wk   = (const float*)d_in[3];
  const float* Wv   = (const float*)d_in[4];
  const float* Wo   = (const float*)d_in[5];
  float* out = (float*)d_out;

  bf16* ws = (bf16*)d_ws;
  bf16* Xb  = ws;                 // 4096*2048
  bf16* Wqb = ws + 8388608;       // 2048*2048 each
  bf16* Wkb = ws + 12582912;
  bf16* Wvb = ws + 16777216;
  bf16* Wob = ws + 20971520;
  bf16* Qb  = ws + 25165824;      // 4096*2048 each
  bf16* Kb  = ws + 33554432;
  bf16* Vb  = ws + 41943040;
  bf16* Ab  = ws + 50331648;      // 4096*2048

  f32_to_bf16_k<<<8192, 256, 0, stream>>>(X,  Xb,  2097152);
  f32_to_bf16_k<<<4096, 256, 0, stream>>>(Wq, Wqb, 1048576);
  f32_to_bf16_k<<<4096, 256, 0, stream>>>(Wk, Wkb, 1048576);
  f32_to_bf16_k<<<4096, 256, 0, stream>>>(Wv, Wvb, 1048576);
  f32_to_bf16_k<<<4096, 256, 0, stream>>>(Wo, Wob, 1048576);

  gemm_bt<bf16><<<dim3(16, 32, 3), 256, 0, stream>>>(
      Xb, Wqb, Wkb, Wvb, Qb, Kb, Vb, 4096, 2048, 2048);

  attn_fwd<<<dim3(32, 32), 256, 0, stream>>>(Qb, Kb, Vb, mask, Ab);

  gemm_bt<float><<<dim3(16, 32, 1), 256, 0, stream>>>(
      Ab, Wob, Wob, Wob, out, out, out, 4096, 2048, 2048);
}